// Round 15
// baseline (161.867 us; speedup 1.0000x reference)
//
#include <hip/hip_runtime.h>

#define Bb 64
#define Nn 8192
#define Ff 32
#define Gg 32
#define G3 (Gg*Gg*Gg)          // 32768
#define NATOM (Bb*Nn)          // 524288
#define NBINS (Bb*G3)          // 2^21

// ---------------- ws layout ----------------
// [0,1024)        centers (fallback only)
// [1024, +8MB)    meta[NBINS] u32: (end_local<<16)|cnt   (end,cnt <= 8192)
// [+2MB)          atomIdx[NATOM] u32 (global atom id, bin-sorted)
static const size_t WS_CENTERS = 0;
static const size_t WS_META    = 1024;
static const size_t WS_AIDX    = WS_META + (size_t)NBINS * 4;
static const size_t WS_NEED    = WS_AIDX + (size_t)NATOM * 4;

// One block per batch (1024 threads, 8 atoms/thread): fp64 centroid ->
// two-pass LDS histogram -> in-LDS scan -> meta + LDS-atomic placement.
// (byte-for-byte the R9 version, passed at 145 us)
__global__ void __launch_bounds__(1024) fused_sort_kernel(const float* __restrict__ coords,
                                                          unsigned* __restrict__ meta,
                                                          unsigned* __restrict__ atomIdx) {
    __shared__ unsigned long long lds8[8192];      // 64 KB, 8B-aligned
    unsigned* hist = (unsigned*)lds8;              // [16384] bins per pass
    double*   dred = (double*)lds8;                // [1024*3] centroid reduction

    const int b = blockIdx.x;
    const int t = threadIdx.x;
    const int wave = t >> 6, lane = t & 63;

    float ax[8], ay[8], az[8];
    const float* cb = coords + (size_t)b * Nn * 3;
    #pragma unroll
    for (int i = 0; i < 8; ++i) {
        const int n = t + 1024 * i;
        ax[i] = cb[n * 3 + 0]; ay[i] = cb[n * 3 + 1]; az[i] = cb[n * 3 + 2];
    }

    double sx = 0.0, sy = 0.0, sz = 0.0;
    #pragma unroll
    for (int i = 0; i < 8; ++i) { sx += (double)ax[i]; sy += (double)ay[i]; sz += (double)az[i]; }
    dred[t * 3 + 0] = sx; dred[t * 3 + 1] = sy; dred[t * 3 + 2] = sz;
    __syncthreads();
    for (int s = 512; s > 0; s >>= 1) {
        if (t < s) {
            dred[t * 3 + 0] += dred[(t + s) * 3 + 0];
            dred[t * 3 + 1] += dred[(t + s) * 3 + 1];
            dred[t * 3 + 2] += dred[(t + s) * 3 + 2];
        }
        __syncthreads();
    }
    const float cx = (float)(dred[0] * (1.0 / Nn));
    const float cy = (float)(dred[1] * (1.0 / Nn));
    const float cz = (float)(dred[2] * (1.0 / Nn));
    __syncthreads();

    unsigned bin[8];
    #pragma unroll
    for (int i = 0; i < 8; ++i) {
        const int ix = min(max((int)((ax[i] - cx) + 16.0f), 0), Gg - 1);
        const int iy = min(max((int)((ay[i] - cy) + 16.0f), 0), Gg - 1);
        const int iz = min(max((int)((az[i] - cz) + 16.0f), 0), Gg - 1);
        bin[i] = ((unsigned)ix << 10) | ((unsigned)iy << 5) | (unsigned)iz;
    }

    unsigned passbase = 0;
    for (int pass = 0; pass < 2; ++pass) {
        const unsigned lo = (unsigned)pass << 14;
        #pragma unroll
        for (int j = 0; j < 16; ++j) hist[t + 1024 * j] = 0u;
        __syncthreads();
        #pragma unroll
        for (int i = 0; i < 8; ++i)
            if ((bin[i] >> 14) == (unsigned)pass) atomicAdd(&hist[bin[i] & 16383u], 1u);
        __syncthreads();

        const int w0 = t * 16;
        unsigned s = 0;
        #pragma unroll
        for (int j = 0; j < 16; ++j) s += hist[w0 + j] & 0xFFFFu;
        unsigned incl = s;
        #pragma unroll
        for (int d = 1; d < 64; d <<= 1) {
            const unsigned u = __shfl_up(incl, d);
            if (lane >= d) incl += u;
        }
        if (lane == 63) hist[wave] = (hist[wave] & 0xFFFFu) | (incl << 16);
        __syncthreads();
        unsigned wbase = 0, tot = 0;
        #pragma unroll
        for (int w = 0; w < 16; ++w) {
            const unsigned wt = hist[w] >> 16;
            if (w < wave) wbase += wt;
            tot += wt;
        }
        unsigned running = passbase + wbase + (incl - s);
        __syncthreads();
        unsigned* mrow = meta + (size_t)b * 32768 + lo;
        #pragma unroll
        for (int j = 0; j < 16; ++j) {
            const unsigned c = hist[w0 + j] & 0xFFFFu;
            hist[w0 + j] = running;
            mrow[w0 + j] = ((running + c) << 16) | c;
            running += c;
        }
        __syncthreads();
        #pragma unroll
        for (int i = 0; i < 8; ++i)
            if ((bin[i] >> 14) == (unsigned)pass) {
                const unsigned pos = atomicAdd(&hist[bin[i] & 16383u], 1u);
                atomIdx[(size_t)b * Nn + pos] = (unsigned)(b * Nn) + (unsigned)(t + 1024 * i);
            }
        __syncthreads();
        passbase = tot;
    }
}

// One thread per output cell (R9 structure, R9 store path). The k-loop is
// 4-deep software-pipelined: 4 atomIdx loads (contiguous, address-known)
// then 32 independent float4 feature loads in flight before any accumulate
// -> dense-wave dependent-chain latency / ~4.
__global__ void __launch_bounds__(256) gather_kernel(const unsigned* __restrict__ meta,
                                                     const unsigned* __restrict__ atomIdx,
                                                     const float* __restrict__ features,
                                                     const float* __restrict__ W,
                                                     const float* __restrict__ bias,
                                                     float* __restrict__ out) {
    const int b = blockIdx.x >> 7;                 // 128 chunks of 256 cells per batch
    const int spatial = ((blockIdx.x & 127) << 8) + threadIdx.x;
    const unsigned m = meta[((size_t)b << 15) + (unsigned)spatial];
    const unsigned k = m & 0xFFFFu;
    float* outb = out + (size_t)b * Ff * G3 + spatial;

    if (!__any((int)k)) {                          // whole wave empty: zero-fill
        #pragma unroll
        for (int f = 0; f < Ff; ++f) outb[(size_t)f * G3] = 0.0f;
        return;
    }

    const unsigned start = ((unsigned)b << 13) + (m >> 16) - k;
    const unsigned* ai = atomIdx + start;
    float acc[Ff];
    #pragma unroll
    for (int j = 0; j < Ff; ++j) acc[j] = 0.0f;

    unsigned i = 0;
    for (; i + 4 <= k; i += 4) {                   // 4-deep pipeline
        const unsigned a0 = ai[i + 0], a1 = ai[i + 1], a2 = ai[i + 2], a3 = ai[i + 3];
        const float4* p0 = reinterpret_cast<const float4*>(features + (size_t)a0 * Ff);
        const float4* p1 = reinterpret_cast<const float4*>(features + (size_t)a1 * Ff);
        const float4* p2 = reinterpret_cast<const float4*>(features + (size_t)a2 * Ff);
        const float4* p3 = reinterpret_cast<const float4*>(features + (size_t)a3 * Ff);
        float4 r0[8], r1[8], r2[8], r3[8];
        #pragma unroll
        for (int q = 0; q < 8; ++q) r0[q] = p0[q];
        #pragma unroll
        for (int q = 0; q < 8; ++q) r1[q] = p1[q];
        #pragma unroll
        for (int q = 0; q < 8; ++q) r2[q] = p2[q];
        #pragma unroll
        for (int q = 0; q < 8; ++q) r3[q] = p3[q];
        #pragma unroll
        for (int q = 0; q < 8; ++q) {
            acc[4 * q + 0] += r0[q].x + r1[q].x + r2[q].x + r3[q].x;
            acc[4 * q + 1] += r0[q].y + r1[q].y + r2[q].y + r3[q].y;
            acc[4 * q + 2] += r0[q].z + r1[q].z + r2[q].z + r3[q].z;
            acc[4 * q + 3] += r0[q].w + r1[q].w + r2[q].w + r3[q].w;
        }
    }
    for (; i < k; ++i) {                           // remainder
        const unsigned a = ai[i];
        const float4* f4 = reinterpret_cast<const float4*>(features + (size_t)a * Ff);
        #pragma unroll
        for (int q = 0; q < 8; ++q) {
            const float4 v = f4[q];
            acc[4 * q + 0] += v.x; acc[4 * q + 1] += v.y;
            acc[4 * q + 2] += v.z; acc[4 * q + 3] += v.w;
        }
    }

    const float kf = (float)k;
    #pragma unroll
    for (int f = 0; f < Ff; f += 4) {              // 4 independent FMA chains
        float v0 = kf * bias[f + 0];
        float v1 = kf * bias[f + 1];
        float v2 = kf * bias[f + 2];
        float v3 = kf * bias[f + 3];
        #pragma unroll
        for (int j = 0; j < Ff; ++j) {
            const float a = acc[j];
            v0 += W[(f + 0) * Ff + j] * a;         // uniform -> s_load, v_fmac v,s,v
            v1 += W[(f + 1) * Ff + j] * a;
            v2 += W[(f + 2) * Ff + j] * a;
            v3 += W[(f + 3) * Ff + j] * a;
        }
        outb[(size_t)(f + 0) * G3] = v0;           // 64 lanes x 4B = 256B/instr, coalesced
        outb[(size_t)(f + 1) * G3] = v1;
        outb[(size_t)(f + 2) * G3] = v2;
        outb[(size_t)(f + 3) * G3] = v3;
    }
}

// ---------- fallback (atomic path) if ws is too small ----------
__global__ void __launch_bounds__(256) centers_kernel(const float* __restrict__ coords,
                                                      float* __restrict__ centers) {
    const int b = blockIdx.x;
    const int t = threadIdx.x;
    double sx = 0.0, sy = 0.0, sz = 0.0;
    const float* cb = coords + (size_t)b * Nn * 3;
    for (int n = t; n < Nn; n += 256) {
        sx += (double)cb[n * 3 + 0];
        sy += (double)cb[n * 3 + 1];
        sz += (double)cb[n * 3 + 2];
    }
    __shared__ double red[256][3];
    red[t][0] = sx; red[t][1] = sy; red[t][2] = sz;
    __syncthreads();
    for (int s = 128; s > 0; s >>= 1) {
        if (t < s) {
            red[t][0] += red[t + s][0];
            red[t][1] += red[t + s][1];
            red[t][2] += red[t + s][2];
        }
        __syncthreads();
    }
    if (t < 3) centers[b * 3 + t] = (float)(red[0][t] * (1.0 / Nn));
}

__global__ void __launch_bounds__(256) scatter_kernel(const float* __restrict__ coords,
                                                      const float* __restrict__ features,
                                                      const float* __restrict__ W,
                                                      const float* __restrict__ bias,
                                                      const float* __restrict__ centers,
                                                      float* __restrict__ out) {
    __shared__ float Wl[Ff * Ff];
    __shared__ float bl[Ff];
    for (int i = threadIdx.x; i < Ff * Ff; i += 256) Wl[i] = W[i];
    if (threadIdx.x < Ff) bl[threadIdx.x] = bias[threadIdx.x];
    __syncthreads();
    const int atom = blockIdx.x * 256 + threadIdx.x;
    const int b = atom >> 13;
    const float cx = centers[b * 3 + 0];
    const float cy = centers[b * 3 + 1];
    const float cz = centers[b * 3 + 2];
    const float* cp = coords + (size_t)atom * 3;
    const int ix = min(max((int)((cp[0] - cx) + 16.0f), 0), Gg - 1);
    const int iy = min(max((int)((cp[1] - cy) + 16.0f), 0), Gg - 1);
    const int iz = min(max((int)((cp[2] - cz) + 16.0f), 0), Gg - 1);
    const int spatial = ix * (Gg * Gg) + iy * Gg + iz;
    float* outb = out + (size_t)b * Ff * G3 + spatial;
    float ft[Ff];
    const float4* f4 = reinterpret_cast<const float4*>(features + (size_t)atom * Ff);
    #pragma unroll
    for (int q = 0; q < 8; ++q) {
        const float4 v = f4[q];
        ft[4 * q + 0] = v.x; ft[4 * q + 1] = v.y;
        ft[4 * q + 2] = v.z; ft[4 * q + 3] = v.w;
    }
    #pragma unroll 4
    for (int fo = 0; fo < Ff; ++fo) {
        float a2 = bl[fo];
        #pragma unroll
        for (int j = 0; j < Ff; ++j) a2 += Wl[fo * Ff + j] * ft[j];
        atomicAdd(outb + (size_t)fo * G3, a2);
    }
}

extern "C" void kernel_launch(void* const* d_in, const int* in_sizes, int n_in,
                              void* d_out, int out_size, void* d_ws, size_t ws_size,
                              hipStream_t stream) {
    const float* coords   = (const float*)d_in[0];
    const float* features = (const float*)d_in[1];
    const float* W        = (const float*)d_in[2];
    const float* bias     = (const float*)d_in[3];
    float* out = (float*)d_out;

    char* ws = (char*)d_ws;

    if (ws_size < WS_NEED) {
        float* centers = (float*)(ws + WS_CENTERS);
        hipMemsetAsync(d_out, 0, (size_t)out_size * sizeof(float), stream);
        centers_kernel<<<Bb, 256, 0, stream>>>(coords, centers);
        scatter_kernel<<<(NATOM) / 256, 256, 0, stream>>>(coords, features, W, bias, centers, out);
        return;
    }

    unsigned* meta    = (unsigned*)(ws + WS_META);
    unsigned* atomIdx = (unsigned*)(ws + WS_AIDX);

    fused_sort_kernel<<<Bb, 1024, 0, stream>>>(coords, meta, atomIdx);
    gather_kernel<<<Bb * (G3 / 256), 256, 0, stream>>>(meta, atomIdx, features, W, bias, out);
}

// Round 16
// 159.999 us; speedup vs baseline: 1.0117x; 1.0117x over previous
//
#include <hip/hip_runtime.h>

#define Bb 64
#define Nn 8192
#define Ff 32
#define Gg 32
#define G3 (Gg*Gg*Gg)          // 32768
#define NATOM (Bb*Nn)          // 524288
#define NBINS (Bb*G3)          // 2^21

// ---------------- ws layout ----------------
// [0,1024)        centers (fallback only)
// [1024, +8MB)    meta[NBINS] u32: (end_local<<16)|cnt   (end,cnt <= 8192)
// [+2MB)          atomIdx[NATOM] u32 (global atom id, bin-sorted)
static const size_t WS_CENTERS = 0;
static const size_t WS_META    = 1024;
static const size_t WS_AIDX    = WS_META + (size_t)NBINS * 4;
static const size_t WS_NEED    = WS_AIDX + (size_t)NATOM * 4;

// One block per batch (1024 threads, 8 atoms/thread): fp64 centroid ->
// two-pass LDS histogram -> in-LDS scan -> meta + LDS-atomic placement.
// (byte-for-byte the R9 version, passed at 145 us)
__global__ void __launch_bounds__(1024) fused_sort_kernel(const float* __restrict__ coords,
                                                          unsigned* __restrict__ meta,
                                                          unsigned* __restrict__ atomIdx) {
    __shared__ unsigned long long lds8[8192];      // 64 KB, 8B-aligned
    unsigned* hist = (unsigned*)lds8;              // [16384] bins per pass
    double*   dred = (double*)lds8;                // [1024*3] centroid reduction

    const int b = blockIdx.x;
    const int t = threadIdx.x;
    const int wave = t >> 6, lane = t & 63;

    float ax[8], ay[8], az[8];
    const float* cb = coords + (size_t)b * Nn * 3;
    #pragma unroll
    for (int i = 0; i < 8; ++i) {
        const int n = t + 1024 * i;
        ax[i] = cb[n * 3 + 0]; ay[i] = cb[n * 3 + 1]; az[i] = cb[n * 3 + 2];
    }

    double sx = 0.0, sy = 0.0, sz = 0.0;
    #pragma unroll
    for (int i = 0; i < 8; ++i) { sx += (double)ax[i]; sy += (double)ay[i]; sz += (double)az[i]; }
    dred[t * 3 + 0] = sx; dred[t * 3 + 1] = sy; dred[t * 3 + 2] = sz;
    __syncthreads();
    for (int s = 512; s > 0; s >>= 1) {
        if (t < s) {
            dred[t * 3 + 0] += dred[(t + s) * 3 + 0];
            dred[t * 3 + 1] += dred[(t + s) * 3 + 1];
            dred[t * 3 + 2] += dred[(t + s) * 3 + 2];
        }
        __syncthreads();
    }
    const float cx = (float)(dred[0] * (1.0 / Nn));
    const float cy = (float)(dred[1] * (1.0 / Nn));
    const float cz = (float)(dred[2] * (1.0 / Nn));
    __syncthreads();

    unsigned bin[8];
    #pragma unroll
    for (int i = 0; i < 8; ++i) {
        const int ix = min(max((int)((ax[i] - cx) + 16.0f), 0), Gg - 1);
        const int iy = min(max((int)((ay[i] - cy) + 16.0f), 0), Gg - 1);
        const int iz = min(max((int)((az[i] - cz) + 16.0f), 0), Gg - 1);
        bin[i] = ((unsigned)ix << 10) | ((unsigned)iy << 5) | (unsigned)iz;
    }

    unsigned passbase = 0;
    for (int pass = 0; pass < 2; ++pass) {
        const unsigned lo = (unsigned)pass << 14;
        #pragma unroll
        for (int j = 0; j < 16; ++j) hist[t + 1024 * j] = 0u;
        __syncthreads();
        #pragma unroll
        for (int i = 0; i < 8; ++i)
            if ((bin[i] >> 14) == (unsigned)pass) atomicAdd(&hist[bin[i] & 16383u], 1u);
        __syncthreads();

        const int w0 = t * 16;
        unsigned s = 0;
        #pragma unroll
        for (int j = 0; j < 16; ++j) s += hist[w0 + j] & 0xFFFFu;
        unsigned incl = s;
        #pragma unroll
        for (int d = 1; d < 64; d <<= 1) {
            const unsigned u = __shfl_up(incl, d);
            if (lane >= d) incl += u;
        }
        if (lane == 63) hist[wave] = (hist[wave] & 0xFFFFu) | (incl << 16);
        __syncthreads();
        unsigned wbase = 0, tot = 0;
        #pragma unroll
        for (int w = 0; w < 16; ++w) {
            const unsigned wt = hist[w] >> 16;
            if (w < wave) wbase += wt;
            tot += wt;
        }
        unsigned running = passbase + wbase + (incl - s);
        __syncthreads();
        unsigned* mrow = meta + (size_t)b * 32768 + lo;
        #pragma unroll
        for (int j = 0; j < 16; ++j) {
            const unsigned c = hist[w0 + j] & 0xFFFFu;
            hist[w0 + j] = running;
            mrow[w0 + j] = ((running + c) << 16) | c;
            running += c;
        }
        __syncthreads();
        #pragma unroll
        for (int i = 0; i < 8; ++i)
            if ((bin[i] >> 14) == (unsigned)pass) {
                const unsigned pos = atomicAdd(&hist[bin[i] & 16383u], 1u);
                atomIdx[(size_t)b * Nn + pos] = (unsigned)(b * Nn) + (unsigned)(t + 1024 * i);
            }
        __syncthreads();
        passbase = tot;
    }
}

// Block = 256 consecutive cells. Per-cell gather+matvec = R9. Output goes
// through a 32 KB block tile [32 f][256 cells] so each wave-level store is
// 64 lanes x dwordx4 = 1 KB CONTIGUOUS within one f-plane (vs R9/R14's
// 256 B/plane bursts) -- tests the write-burst-granularity theory.
// Fully-empty blocks skip LDS and run a pure 1 KB-burst zero fill.
__global__ void __launch_bounds__(256) gather_kernel(const unsigned* __restrict__ meta,
                                                     const unsigned* __restrict__ atomIdx,
                                                     const float* __restrict__ features,
                                                     const float* __restrict__ W,
                                                     const float* __restrict__ bias,
                                                     float* __restrict__ out) {
    __shared__ float tile[Ff * 256];               // 32 KB [f][cell]
    __shared__ unsigned wflag[4];
    const int b = blockIdx.x >> 7;                 // 128 blocks of 256 cells per batch
    const int spatial0 = (blockIdx.x & 127) << 8;
    const int t = threadIdx.x, wave = t >> 6, lane = t & 63;
    const unsigned m = meta[((size_t)b << 15) + (unsigned)(spatial0 + t)];
    const unsigned k = m & 0xFFFFu;

    if (lane == 0) wflag[wave] = 0u;
    __syncthreads();
    if (__any((int)k) && lane == 0) wflag[wave] = 1u;
    __syncthreads();
    const bool blockEmpty = (wflag[0] | wflag[1] | wflag[2] | wflag[3]) == 0u;

    if (blockEmpty) {                              // block-uniform branch
        const float4 z4 = make_float4(0.f, 0.f, 0.f, 0.f);
        #pragma unroll
        for (int it = 0; it < 8; ++it) {
            const int f = wave + 4 * it;
            float4* dst = reinterpret_cast<float4*>(out + (size_t)(b * Ff + f) * G3 + spatial0);
            dst[lane] = z4;                        // 64 lanes x 16 B = 1 KB contiguous
        }
        return;
    }

    // ---- per-cell gather + matvec (R9 path) ----
    float acc[Ff];
    #pragma unroll
    for (int j = 0; j < Ff; ++j) acc[j] = 0.0f;
    if (k) {
        const unsigned start = ((unsigned)b << 13) + (m >> 16) - k;
        for (unsigned i = 0; i < k; ++i) {
            const unsigned a = atomIdx[start + i];
            const float4* f4 = reinterpret_cast<const float4*>(features + (size_t)a * Ff);
            #pragma unroll
            for (int q = 0; q < 8; ++q) {
                const float4 v = f4[q];
                acc[4 * q + 0] += v.x; acc[4 * q + 1] += v.y;
                acc[4 * q + 2] += v.z; acc[4 * q + 3] += v.w;
            }
        }
    }
    const float kf = (float)k;
    #pragma unroll
    for (int f = 0; f < Ff; f += 4) {              // 4 independent FMA chains
        float v0 = kf * bias[f + 0];
        float v1 = kf * bias[f + 1];
        float v2 = kf * bias[f + 2];
        float v3 = kf * bias[f + 3];
        #pragma unroll
        for (int j = 0; j < Ff; ++j) {
            const float a = acc[j];
            v0 += W[(f + 0) * Ff + j] * a;         // uniform -> s_load, v_fmac v,s,v
            v1 += W[(f + 1) * Ff + j] * a;
            v2 += W[(f + 2) * Ff + j] * a;
            v3 += W[(f + 3) * Ff + j] * a;
        }
        tile[(f + 0) * 256 + t] = v0;              // 2 lanes/bank: free
        tile[(f + 1) * 256 + t] = v1;
        tile[(f + 2) * 256 + t] = v2;
        tile[(f + 3) * 256 + t] = v3;
    }
    __syncthreads();

    // ---- write-out: wave covers one full plane per iteration ----
    #pragma unroll
    for (int it = 0; it < 8; ++it) {
        const int f = wave + 4 * it;
        const float4 v = *reinterpret_cast<const float4*>(&tile[f * 256 + lane * 4]);
        float4* dst = reinterpret_cast<float4*>(out + (size_t)(b * Ff + f) * G3 + spatial0);
        dst[lane] = v;                             // 1 KB contiguous per instruction
    }
}

// ---------- fallback (atomic path) if ws is too small ----------
__global__ void __launch_bounds__(256) centers_kernel(const float* __restrict__ coords,
                                                      float* __restrict__ centers) {
    const int b = blockIdx.x;
    const int t = threadIdx.x;
    double sx = 0.0, sy = 0.0, sz = 0.0;
    const float* cb = coords + (size_t)b * Nn * 3;
    for (int n = t; n < Nn; n += 256) {
        sx += (double)cb[n * 3 + 0];
        sy += (double)cb[n * 3 + 1];
        sz += (double)cb[n * 3 + 2];
    }
    __shared__ double red[256][3];
    red[t][0] = sx; red[t][1] = sy; red[t][2] = sz;
    __syncthreads();
    for (int s = 128; s > 0; s >>= 1) {
        if (t < s) {
            red[t][0] += red[t + s][0];
            red[t][1] += red[t + s][1];
            red[t][2] += red[t + s][2];
        }
        __syncthreads();
    }
    if (t < 3) centers[b * 3 + t] = (float)(red[0][t] * (1.0 / Nn));
}

__global__ void __launch_bounds__(256) scatter_kernel(const float* __restrict__ coords,
                                                      const float* __restrict__ features,
                                                      const float* __restrict__ W,
                                                      const float* __restrict__ bias,
                                                      const float* __restrict__ centers,
                                                      float* __restrict__ out) {
    __shared__ float Wl[Ff * Ff];
    __shared__ float bl[Ff];
    for (int i = threadIdx.x; i < Ff * Ff; i += 256) Wl[i] = W[i];
    if (threadIdx.x < Ff) bl[threadIdx.x] = bias[threadIdx.x];
    __syncthreads();
    const int atom = blockIdx.x * 256 + threadIdx.x;
    const int b = atom >> 13;
    const float cx = centers[b * 3 + 0];
    const float cy = centers[b * 3 + 1];
    const float cz = centers[b * 3 + 2];
    const float* cp = coords + (size_t)atom * 3;
    const int ix = min(max((int)((cp[0] - cx) + 16.0f), 0), Gg - 1);
    const int iy = min(max((int)((cp[1] - cy) + 16.0f), 0), Gg - 1);
    const int iz = min(max((int)((cp[2] - cz) + 16.0f), 0), Gg - 1);
    const int spatial = ix * (Gg * Gg) + iy * Gg + iz;
    float* outb = out + (size_t)b * Ff * G3 + spatial;
    float ft[Ff];
    const float4* f4 = reinterpret_cast<const float4*>(features + (size_t)atom * Ff);
    #pragma unroll
    for (int q = 0; q < 8; ++q) {
        const float4 v = f4[q];
        ft[4 * q + 0] = v.x; ft[4 * q + 1] = v.y;
        ft[4 * q + 2] = v.z; ft[4 * q + 3] = v.w;
    }
    #pragma unroll 4
    for (int fo = 0; fo < Ff; ++fo) {
        float a2 = bl[fo];
        #pragma unroll
        for (int j = 0; j < Ff; ++j) a2 += Wl[fo * Ff + j] * ft[j];
        atomicAdd(outb + (size_t)fo * G3, a2);
    }
}

extern "C" void kernel_launch(void* const* d_in, const int* in_sizes, int n_in,
                              void* d_out, int out_size, void* d_ws, size_t ws_size,
                              hipStream_t stream) {
    const float* coords   = (const float*)d_in[0];
    const float* features = (const float*)d_in[1];
    const float* W        = (const float*)d_in[2];
    const float* bias     = (const float*)d_in[3];
    float* out = (float*)d_out;

    char* ws = (char*)d_ws;

    if (ws_size < WS_NEED) {
        float* centers = (float*)(ws + WS_CENTERS);
        hipMemsetAsync(d_out, 0, (size_t)out_size * sizeof(float), stream);
        centers_kernel<<<Bb, 256, 0, stream>>>(coords, centers);
        scatter_kernel<<<(NATOM) / 256, 256, 0, stream>>>(coords, features, W, bias, centers, out);
        return;
    }

    unsigned* meta    = (unsigned*)(ws + WS_META);
    unsigned* atomIdx = (unsigned*)(ws + WS_AIDX);

    fused_sort_kernel<<<Bb, 1024, 0, stream>>>(coords, meta, atomIdx);
    gather_kernel<<<Bb * (G3 / 256), 256, 0, stream>>>(meta, atomIdx, features, W, bias, out);
}